// Round 6
// baseline (508.701 us; speedup 1.0000x reference)
//
#include <hip/hip_runtime.h>
#include <hip/hip_cooperative_groups.h>

// DynamicGCN: x[100000,384] fp32 -> Linear(384,64) -> GCNConv(64,64) -> ReLU -> GCNConv(64,64)
// Round 12: full-occupancy cooperative gather section (R4 retried without the
// self-inflicted 1024-block cap), R1-verified math everywhere else.
//   D0 memset : deg=0, count=0 (800 KB)
//   D1 degwf  : deg atomics (3125 blk) || Wf = Wm@W1 (6 blk, 8KB LDS)
//   D2 fill   : records {src, coef}, coef = rsqrt(deg_s+1)*w*rsqrt(deg_d+1)
//   D3 gemm   : hb = x @ Wf (ONE K=384 MFMA GEMM)
//   D4 coop   : [gather1: aggb = relu(A*hb + rowsum*bmW1 + b1)] -> grid.sync ->
//               [g2gemm: out = (A*aggb)@W2 + b2]   grid = occ-query * 256 (~2048)
// Self-loop +1 folded at rsqrt sites. bf16 intermediates, fp32 accumulation.

#define NN 100000
#define NE 800000
#define BC 32          // bucket capacity per dst row (16 int4); P(Poisson(8)>32) ~ 1e-12

typedef unsigned short u16;
typedef __attribute__((ext_vector_type(8))) short short8;   // 8 bf16 (MFMA A/B frag)
typedef __attribute__((ext_vector_type(4))) float f4;       // MFMA C/D frag
typedef __attribute__((ext_vector_type(8))) unsigned short u16x8;

__device__ __forceinline__ u16 f2b(float f) {   // RNE fp32 -> bf16
    unsigned int x = __float_as_uint(f);
    x += 0x7fffu + ((x >> 16) & 1u);
    return (u16)(x >> 16);
}
__device__ __forceinline__ float b2f(u16 u) {
    return __uint_as_float(((unsigned int)u) << 16);
}

// ---- D1: blocks 0..3124 deg atomics; blocks 3125..3130 Wf = Wm@W1 ---------
__global__ __launch_bounds__(256) void degwf_k(const int* __restrict__ ei,
                                               const float* __restrict__ ew,
                                               float* __restrict__ deg,
                                               const float* __restrict__ Wm,
                                               const float* __restrict__ W1,
                                               float* __restrict__ Wf) {
    __shared__ u16 Blds[2 * 256 * 8];           // 8 KB (Wf blocks only)
    int tid = threadIdx.x, bid = blockIdx.x;
    if (bid < 3125) {                           // 3125*256 == NE exact
        int e = bid * 256 + tid;
        atomicAdd(&deg[ei[NE + e]], ew[e]);
        return;
    }
    // ---- Wf = Wm[384,64] @ W1[64,64], fp32 out (24 rowtiles over 6 blocks) ----
    for (int idx = tid; idx < 2 * 256; idx += 256) {
        int kt = idx >> 8, rem = idx & 255;
        int ct = rem >> 6, ln = rem & 63;
        int kb = kt * 32 + (ln >> 4) * 8;
        int col = ct * 16 + (ln & 15);
#pragma unroll
        for (int j = 0; j < 8; j++)
            Blds[idx * 8 + j] = f2b(W1[(kb + j) * 64 + col]);
    }
    __syncthreads();
    int wave = tid >> 6, lane = tid & 63;
    int rowtile = (bid - 3125) * 4 + wave;      // 0..23
    int rowbase = rowtile * 16;
    int m = lane & 15, quad = lane >> 4;
    f4 acc[4];
#pragma unroll
    for (int ct = 0; ct < 4; ct++) acc[ct] = 0.0f;
    const short8* Bfrag = (const short8*)Blds;
#pragma unroll
    for (int kt = 0; kt < 2; kt++) {
        const f4* p = (const f4*)&Wm[(size_t)(rowbase + m) * 64 + kt * 32 + quad * 8];
        f4 v0 = p[0], v1 = p[1];
        short8 af;
#pragma unroll
        for (int j = 0; j < 4; j++) {
            af[j]     = (short)f2b(v0[j]);
            af[4 + j] = (short)f2b(v1[j]);
        }
#pragma unroll
        for (int ct = 0; ct < 4; ct++)
            acc[ct] = __builtin_amdgcn_mfma_f32_16x16x32_bf16(af, Bfrag[(kt * 4 + ct) * 64 + lane], acc[ct], 0, 0, 0);
    }
#pragma unroll
    for (int ct = 0; ct < 4; ct++) {
        int col = ct * 16 + m;
#pragma unroll
        for (int r = 0; r < 4; r++)
            Wf[(size_t)(rowbase + quad * 4 + r) * 64 + col] = acc[ct][r];
    }
}

// ---- D2 fill: e2[dst*BC+pos] = {src, coef}, full precomputed coef ---------
__global__ __launch_bounds__(256) void fill_k(const int* __restrict__ ei,
                                              const float* __restrict__ ew,
                                              const float* __restrict__ deg,
                                              int* __restrict__ count,
                                              int2* __restrict__ e2) {
    int e = blockIdx.x * 256 + threadIdx.x;     // grid exact
    int src = ei[e];
    int dst = ei[NE + e];
    float coef = rsqrtf(deg[src] + 1.0f) * ew[e] * rsqrtf(deg[dst] + 1.0f);
    int pos = atomicAdd(&count[dst], 1);
    if (pos < BC)                               // effectively never
        e2[(size_t)dst * BC + pos] = make_int2(src, __float_as_int(coef));
}

// ---- D3 MFMA GEMM: hb = x[100000,384] @ Wf[384,64], bf16 out --------------
__global__ __launch_bounds__(256) void gcn_gemm(const float* __restrict__ Ain,
                                                const float* __restrict__ Wg,
                                                u16* __restrict__ outb) {
    constexpr int KT = 12;
    __shared__ u16 Blds[KT * 256 * 8];
    int tid = threadIdx.x;
    for (int idx = tid; idx < KT * 256; idx += 256) {
        int kt = idx >> 8, rem = idx & 255;
        int ct = rem >> 6, ln = rem & 63;
        int kb = kt * 32 + (ln >> 4) * 8;
        int col = ct * 16 + (ln & 15);
#pragma unroll
        for (int j = 0; j < 8; j++)
            Blds[idx * 8 + j] = f2b(Wg[(kb + j) * 64 + col]);
    }
    __syncthreads();

    int wave = tid >> 6, lane = tid & 63;
    int rowtile = blockIdx.x * 4 + wave;
    if (rowtile >= 6250) return;
    int rowbase = rowtile * 16;
    int m = lane & 15, quad = lane >> 4;

    f4 acc[4];
#pragma unroll
    for (int ct = 0; ct < 4; ct++) acc[ct] = 0.0f;

    const short8* Bfrag = (const short8*)Blds;
#pragma unroll
    for (int kt = 0; kt < KT; kt++) {
        const f4* p = (const f4*)&Ain[(size_t)(rowbase + m) * 384 + kt * 32 + quad * 8];
        f4 v0 = p[0], v1 = p[1];
        short8 af;
#pragma unroll
        for (int j = 0; j < 4; j++) {
            af[j]     = (short)f2b(v0[j]);
            af[4 + j] = (short)f2b(v1[j]);
        }
#pragma unroll
        for (int ct = 0; ct < 4; ct++)
            acc[ct] = __builtin_amdgcn_mfma_f32_16x16x32_bf16(af, Bfrag[(kt * 4 + ct) * 64 + lane], acc[ct], 0, 0, 0);
    }

#pragma unroll
    for (int ct = 0; ct < 4; ct++) {
        int col = ct * 16 + m;
#pragma unroll
        for (int r = 0; r < 4; r++)
            outb[(size_t)(rowbase + quad * 4 + r) * 64 + col] = f2b(acc[ct][r]);
    }
}

// ---- gather core: 8 threads/row, 8 ch; unconditional paired int4 loads,
// value-side masking (invalid -> src=dst, c=0; addresses always in-row).
__device__ __forceinline__ void gatherC(const int2* __restrict__ eb, int cntv, int dst,
                                        const u16* __restrict__ hb, int ch,
                                        float* __restrict__ acc, float& cs) {
    const int4* eb4 = (const int4*)eb;          // 16 int4 per bucket row
    for (int i = 0; i < cntv; i += 8) {
        int4 q[4];
#pragma unroll
        for (int p = 0; p < 4; p++) q[p] = eb4[(i >> 1) + p];
        int s[8];
        float c[8];
#pragma unroll
        for (int p = 0; p < 4; p++) {
            int t0 = i + 2 * p;
            bool v0 = t0 < cntv, v1 = (t0 + 1) < cntv;
            s[2 * p]     = v0 ? q[p].x : dst;
            c[2 * p]     = v0 ? __int_as_float(q[p].y) : 0.0f;
            s[2 * p + 1] = v1 ? q[p].z : dst;
            c[2 * p + 1] = v1 ? __int_as_float(q[p].w) : 0.0f;
        }
        u16x8 hv[8];
#pragma unroll
        for (int t = 0; t < 8; t++)
            hv[t] = *(const u16x8*)&hb[(size_t)s[t] * 64 + ch * 8];
#pragma unroll
        for (int t = 0; t < 8; t++) {
            cs += c[t];
#pragma unroll
            for (int j = 0; j < 8; j++)
                acc[j] = fmaf(c[t], b2f(hv[t][j]), acc[j]);
        }
    }
}

__device__ __forceinline__ void fillW(u16* Wlds, const float* __restrict__ W, int tid) {
    for (int idx = tid; idx < 2 * 256; idx += 256) {
        int kt = idx >> 8, rem = idx & 255;
        int ct = rem >> 6, ln = rem & 63;
        int kb = kt * 32 + (ln >> 4) * 8;
        int col = ct * 16 + (ln & 15);
#pragma unroll
        for (int j = 0; j < 8; j++)
            Wlds[idx * 8 + j] = f2b(W[(size_t)(kb + j) * 64 + col]);
    }
}

// ---- D4 cooperative: gather1 (barrier-free) -> grid.sync -> g2gemm --------
__global__ __launch_bounds__(256) void coop_k(const int2* __restrict__ e2,
                                              const int* __restrict__ count,
                                              const float* __restrict__ deg,
                                              const u16* __restrict__ hb,
                                              const float* __restrict__ bm,
                                              const float* __restrict__ W1,
                                              const float* __restrict__ b1,
                                              u16* __restrict__ aggb,
                                              const float* __restrict__ W2,
                                              const float* __restrict__ b2,
                                              float* __restrict__ out) {
    cooperative_groups::grid_group grid = cooperative_groups::this_grid();
    __shared__ float bmw1s[64];
    __shared__ u16 Wlds[4096];                  // 8 KB swizzled W2 frags
    __shared__ u16 Atile[32][72];               // 32x64 bf16, +8 pad
    int tid = threadIdx.x;
    int rt = tid >> 3, ch = tid & 7;
    int wave = tid >> 6, lane = tid & 63;
    int m = lane & 15, quad = lane >> 4;
    int stride = gridDim.x;

    // ---- phase A: aggb = relu(A_n*hb + rowsum(A_n)*bmW1 + b1) -------------
    if (tid < 64) {
        float a = 0.0f;
#pragma unroll 8
        for (int k = 0; k < 64; k++) a = fmaf(bm[k], W1[k * 64 + tid], a);
        bmw1s[tid] = a;
    }
    __syncthreads();
    float bmv[8], b1v[8];
#pragma unroll
    for (int j = 0; j < 8; j++) { bmv[j] = bmw1s[ch * 8 + j]; b1v[j] = b1[ch * 8 + j]; }

    for (int g = blockIdx.x; g < 3125; g += stride) {
        int dst = g * 32 + rt;
        int cntv = min(count[dst], BC);
        float dd = 1.0f / (deg[dst] + 1.0f);    // dinv^2 (self-loop folded)
        u16x8 hs = *(const u16x8*)&hb[(size_t)dst * 64 + ch * 8];
        float acc[8] = {0, 0, 0, 0, 0, 0, 0, 0};
        float cs = 0.0f;
        gatherC(&e2[(size_t)dst * BC], cntv, dst, hb, ch, acc, cs);
        float s = dd + cs;                      // normalized-adjacency rowsum
        u16x8 o;
#pragma unroll
        for (int j = 0; j < 8; j++) {
            float v = fmaf(dd, b2f(hs[j]), acc[j]);
            o[j] = f2b(fmaxf(fmaf(s, bmv[j], v) + b1v[j], 0.0f));
        }
        ((u16x8*)aggb)[(size_t)dst * 8 + ch] = o;
    }

    __threadfence();
    grid.sync();

    // ---- phase B: out = (A_n*aggb)@W2 + b2 --------------------------------
    fillW(Wlds, W2, tid);
    __syncthreads();

    for (int g = blockIdx.x; g < 3125; g += stride) {
        int dst = g * 32 + rt;
        int cntv = min(count[dst], BC);
        float dd = 1.0f / (deg[dst] + 1.0f);
        u16x8 hs = *(const u16x8*)&aggb[(size_t)dst * 64 + ch * 8];
        float acc[8] = {0, 0, 0, 0, 0, 0, 0, 0};
        float cs = 0.0f;
        gatherC(&e2[(size_t)dst * BC], cntv, dst, aggb, ch, acc, cs);
        u16x8 o;
#pragma unroll
        for (int j = 0; j < 8; j++)
            o[j] = f2b(fmaf(dd, b2f(hs[j]), acc[j]));
        *(u16x8*)&Atile[rt][ch * 8] = o;
        __syncthreads();
        if (tid < 128) {                        // waves 0,1: (Atile)@W2 + b2
            int rowoff = wave * 16;
            f4 cacc[4];
#pragma unroll
            for (int ct = 0; ct < 4; ct++) cacc[ct] = 0.0f;
            const short8* Bfrag = (const short8*)Wlds;
#pragma unroll
            for (int kt = 0; kt < 2; kt++) {
                short8 af = *(const short8*)&Atile[rowoff + m][kt * 32 + quad * 8];
#pragma unroll
                for (int ct = 0; ct < 4; ct++)
                    cacc[ct] = __builtin_amdgcn_mfma_f32_16x16x32_bf16(af, Bfrag[(kt * 4 + ct) * 64 + lane], cacc[ct], 0, 0, 0);
            }
#pragma unroll
            for (int ct = 0; ct < 4; ct++) {
                int col = ct * 16 + m;
                float bc = b2[col];
#pragma unroll
                for (int rr = 0; rr < 4; rr++)
                    out[(size_t)(g * 32 + rowoff + quad * 4 + rr) * 64 + col] = cacc[ct][rr] + bc;
            }
        }
        __syncthreads();
    }
}

extern "C" void kernel_launch(void* const* d_in, const int* in_sizes, int n_in,
                              void* d_out, int out_size, void* d_ws, size_t ws_size,
                              hipStream_t stream) {
    const float* x  = (const float*)d_in[0];
    const int*   ei = (const int*)d_in[1];
    const float* ew = (const float*)d_in[2];
    const float* Wm = (const float*)d_in[3];
    const float* bm = (const float*)d_in[4];
    const float* W1 = (const float*)d_in[5];
    const float* b1 = (const float*)d_in[6];
    const float* W2 = (const float*)d_in[7];
    const float* b2 = (const float*)d_in[8];
    float* out = (float*)d_out;

    // ws layout (offsets in bytes)
    char*  w     = (char*)d_ws;
    float* deg   = (float*)(w);                 // NN f32 (400 KB)
    int*   count = (int*)(w + 400000);          // NN i32 (contiguous with deg)
    float* Wf    = (float*)(w + (1 << 20));     // 384*64 f32 (98 KB)
    int2*  e2    = (int2*)(w + (4 << 20));      // NN*BC int2 (25.6 MB)
    u16*   hb    = (u16*)(w + (64u << 20));     // NN*64 bf16 (12.8 MB)
    u16*   aggb  = (u16*)(w + (80u << 20));     // NN*64 bf16

    // D0: zero deg+count (800 KB contiguous)
    hipMemsetAsync(w, 0, 800000, stream);
    // D1: deg atomics || Wf = Wm@W1
    degwf_k<<<3131, 256, 0, stream>>>(ei, ew, deg, Wm, W1, Wf);
    // D2: records {src, coef}
    fill_k<<<3125, 256, 0, stream>>>(ei, ew, deg, count, e2);
    // D3: hb = x @ Wf
    gcn_gemm<<<1563, 256, 0, stream>>>(x, Wf, hb);
    // D4: cooperative gather1 -> grid.sync -> g2gemm  (full occupancy grid)
    int nb = 0;
    hipOccupancyMaxActiveBlocksPerMultiprocessor(&nb, (const void*)coop_k, 256, 0);
    if (nb < 1) nb = 1;
    int cgrid = nb * 256;
    if (cgrid > 3125) cgrid = 3125;
    void* args[] = {(void*)&e2, (void*)&count, (void*)&deg, (void*)&hb, (void*)&bm,
                    (void*)&W1, (void*)&b1, (void*)&aggb, (void*)&W2, (void*)&b2, (void*)&out};
    hipLaunchCooperativeKernel((const void*)coop_k, dim3(cgrid), dim3(256), args, 0, stream);
}

// Round 7
// 379.223 us; speedup vs baseline: 1.3414x; 1.3414x over previous
//
#include <hip/hip_runtime.h>

// DynamicGCN: x[100000,384] fp32 -> Linear(384,64) -> GCNConv(64,64) -> ReLU -> GCNConv(64,64)
// Round 13: regular launches only (coop carried ~100us fixed overhead), with
// fill || gemm overlapped in one dispatch (complementary pipes, 16KB LDS each).
//   D0 memset   : deg=0, count=0 (800 KB)
//   D1 degwf    : deg atomics (3125 blk) || Wf = Wm@W1 (6 blk, 8KB LDS)
//   D2 fillgemm : blocks 0..1562 hb = x@Wf (16KB LDS, 3 staged chunks);
//                 blocks 1563..4687 fill records {src, coef}
//   D3 gather1  : aggb = relu(A*hb + rowsum*bmW1 + b1)          (bf16)
//   D4 g2gemm   : out = (A*aggb)@W2 + b2                        (fp32)
// Gathers are at the measured random-line-throughput floor (~200us combined);
// this round recovers the serial preprocessing slack instead.

#define NN 100000
#define NE 800000
#define BC 32          // bucket capacity per dst row (16 int4); P(Poisson(8)>32) ~ 1e-12

typedef unsigned short u16;
typedef __attribute__((ext_vector_type(8))) short short8;   // 8 bf16 (MFMA A/B frag)
typedef __attribute__((ext_vector_type(4))) float f4;       // MFMA C/D frag
typedef __attribute__((ext_vector_type(8))) unsigned short u16x8;

__device__ __forceinline__ u16 f2b(float f) {   // RNE fp32 -> bf16
    unsigned int x = __float_as_uint(f);
    x += 0x7fffu + ((x >> 16) & 1u);
    return (u16)(x >> 16);
}
__device__ __forceinline__ float b2f(u16 u) {
    return __uint_as_float(((unsigned int)u) << 16);
}

// ---- D1: blocks 0..3124 deg atomics; blocks 3125..3130 Wf = Wm@W1 ---------
__global__ __launch_bounds__(256) void degwf_k(const int* __restrict__ ei,
                                               const float* __restrict__ ew,
                                               float* __restrict__ deg,
                                               const float* __restrict__ Wm,
                                               const float* __restrict__ W1,
                                               float* __restrict__ Wf) {
    __shared__ u16 Blds[2 * 256 * 8];           // 8 KB (Wf blocks only)
    int tid = threadIdx.x, bid = blockIdx.x;
    if (bid < 3125) {                           // 3125*256 == NE exact
        int e = bid * 256 + tid;
        atomicAdd(&deg[ei[NE + e]], ew[e]);
        return;
    }
    // ---- Wf = Wm[384,64] @ W1[64,64], fp32 out (24 rowtiles over 6 blocks) ----
    for (int idx = tid; idx < 2 * 256; idx += 256) {
        int kt = idx >> 8, rem = idx & 255;
        int ct = rem >> 6, ln = rem & 63;
        int kb = kt * 32 + (ln >> 4) * 8;
        int col = ct * 16 + (ln & 15);
#pragma unroll
        for (int j = 0; j < 8; j++)
            Blds[idx * 8 + j] = f2b(W1[(kb + j) * 64 + col]);
    }
    __syncthreads();
    int wave = tid >> 6, lane = tid & 63;
    int rowtile = (bid - 3125) * 4 + wave;      // 0..23
    int rowbase = rowtile * 16;
    int m = lane & 15, quad = lane >> 4;
    f4 acc[4];
#pragma unroll
    for (int ct = 0; ct < 4; ct++) acc[ct] = 0.0f;
    const short8* Bfrag = (const short8*)Blds;
#pragma unroll
    for (int kt = 0; kt < 2; kt++) {
        const f4* p = (const f4*)&Wm[(size_t)(rowbase + m) * 64 + kt * 32 + quad * 8];
        f4 v0 = p[0], v1 = p[1];
        short8 af;
#pragma unroll
        for (int j = 0; j < 4; j++) {
            af[j]     = (short)f2b(v0[j]);
            af[4 + j] = (short)f2b(v1[j]);
        }
#pragma unroll
        for (int ct = 0; ct < 4; ct++)
            acc[ct] = __builtin_amdgcn_mfma_f32_16x16x32_bf16(af, Bfrag[(kt * 4 + ct) * 64 + lane], acc[ct], 0, 0, 0);
    }
#pragma unroll
    for (int ct = 0; ct < 4; ct++) {
        int col = ct * 16 + m;
#pragma unroll
        for (int r = 0; r < 4; r++)
            Wf[(size_t)(rowbase + quad * 4 + r) * 64 + col] = acc[ct][r];
    }
}

// ---- D2: blocks 0..1562 gemm hb = x@Wf (16KB LDS, 3 chunks);
//          blocks 1563..4687 fill records {src, coef} -----------------------
__global__ __launch_bounds__(256) void fillgemm_k(const int* __restrict__ ei,
                                                  const float* __restrict__ ew,
                                                  const float* __restrict__ deg,
                                                  int* __restrict__ count,
                                                  int2* __restrict__ e2,
                                                  const float* __restrict__ x,
                                                  const float* __restrict__ Wf,
                                                  u16* __restrict__ hb) {
    __shared__ u16 Blds[4 * 256 * 8];           // 16 KB
    int tid = threadIdx.x, bid = blockIdx.x;
    if (bid >= 1563) {                          // fill: (4688-1563)*256 == NE exact
        int e = (bid - 1563) * 256 + tid;
        int src = ei[e];
        int dst = ei[NE + e];
        float coef = rsqrtf(deg[src] + 1.0f) * ew[e] * rsqrtf(deg[dst] + 1.0f);
        int pos = atomicAdd(&count[dst], 1);
        if (pos < BC)                           // effectively never
            e2[(size_t)dst * BC + pos] = make_int2(src, __float_as_int(coef));
        return;
    }
    // ---- gemm: hb = x[100000,384] @ Wf[384,64], bf16 out, 3 LDS chunks ----
    int wave = tid >> 6, lane = tid & 63;
    int rowtile = bid * 4 + wave;
    bool act = rowtile < 6250;
    int rowbase = (act ? rowtile : 6249) * 16;
    int m = lane & 15, quad = lane >> 4;

    f4 acc[4];
#pragma unroll
    for (int ct = 0; ct < 4; ct++) acc[ct] = 0.0f;
    const short8* Bfrag = (const short8*)Blds;

#pragma unroll
    for (int chunk = 0; chunk < 3; chunk++) {
        for (int idx = tid; idx < 4 * 256; idx += 256) {
            int ktl = idx >> 8, rem = idx & 255;
            int ct = rem >> 6, ln = rem & 63;
            int kb = (chunk * 4 + ktl) * 32 + (ln >> 4) * 8;
            int col = ct * 16 + (ln & 15);
#pragma unroll
            for (int j = 0; j < 8; j++)
                Blds[idx * 8 + j] = f2b(Wf[(size_t)(kb + j) * 64 + col]);
        }
        __syncthreads();
#pragma unroll
        for (int ktl = 0; ktl < 4; ktl++) {
            const f4* p = (const f4*)&x[(size_t)(rowbase + m) * 384 + (chunk * 4 + ktl) * 32 + quad * 8];
            f4 v0 = p[0], v1 = p[1];
            short8 af;
#pragma unroll
            for (int j = 0; j < 4; j++) {
                af[j]     = (short)f2b(v0[j]);
                af[4 + j] = (short)f2b(v1[j]);
            }
#pragma unroll
            for (int ct = 0; ct < 4; ct++)
                acc[ct] = __builtin_amdgcn_mfma_f32_16x16x32_bf16(af, Bfrag[(ktl * 4 + ct) * 64 + lane], acc[ct], 0, 0, 0);
        }
        __syncthreads();
    }

    if (act) {
#pragma unroll
        for (int ct = 0; ct < 4; ct++) {
            int col = ct * 16 + m;
#pragma unroll
            for (int r = 0; r < 4; r++)
                hb[(size_t)(rowbase + quad * 4 + r) * 64 + col] = f2b(acc[ct][r]);
        }
    }
}

// ---- gather core: 8 threads/row, 8 ch; unconditional paired int4 loads,
// value-side masking (invalid -> src=dst, c=0; addresses always in-row).
__device__ __forceinline__ void gatherC(const int2* __restrict__ eb, int cntv, int dst,
                                        const u16* __restrict__ hb, int ch,
                                        float* __restrict__ acc, float& cs) {
    const int4* eb4 = (const int4*)eb;          // 16 int4 per bucket row
    for (int i = 0; i < cntv; i += 8) {
        int4 q[4];
#pragma unroll
        for (int p = 0; p < 4; p++) q[p] = eb4[(i >> 1) + p];
        int s[8];
        float c[8];
#pragma unroll
        for (int p = 0; p < 4; p++) {
            int t0 = i + 2 * p;
            bool v0 = t0 < cntv, v1 = (t0 + 1) < cntv;
            s[2 * p]     = v0 ? q[p].x : dst;
            c[2 * p]     = v0 ? __int_as_float(q[p].y) : 0.0f;
            s[2 * p + 1] = v1 ? q[p].z : dst;
            c[2 * p + 1] = v1 ? __int_as_float(q[p].w) : 0.0f;
        }
        u16x8 hv[8];
#pragma unroll
        for (int t = 0; t < 8; t++)
            hv[t] = *(const u16x8*)&hb[(size_t)s[t] * 64 + ch * 8];
#pragma unroll
        for (int t = 0; t < 8; t++) {
            cs += c[t];
#pragma unroll
            for (int j = 0; j < 8; j++)
                acc[j] = fmaf(c[t], b2f(hv[t][j]), acc[j]);
        }
    }
}

// ---- D3 gather1: aggb = relu(A_n*hb + rowsum(A_n)*bmW1 + b1), bf16 --------
__global__ __launch_bounds__(256) void gather1_k(const int2* __restrict__ e2,
                                                 const int* __restrict__ count,
                                                 const float* __restrict__ deg,
                                                 const u16* __restrict__ hb,
                                                 const float* __restrict__ bm,
                                                 const float* __restrict__ W1,
                                                 const float* __restrict__ b1,
                                                 u16* __restrict__ aggb) {
    __shared__ float bmw1s[64];
    int tid = threadIdx.x;
    if (tid < 64) {
        float a = 0.0f;
#pragma unroll 8
        for (int k = 0; k < 64; k++) a = fmaf(bm[k], W1[k * 64 + tid], a);
        bmw1s[tid] = a;
    }
    __syncthreads();

    int rt = tid >> 3, ch = tid & 7;
    int dst = blockIdx.x * 32 + rt;            // grid exact: 3125*32 == NN
    int cntv = min(count[dst], BC);
    float dd = 1.0f / (deg[dst] + 1.0f);       // dinv^2 (self-loop folded)
    u16x8 hs = *(const u16x8*)&hb[(size_t)dst * 64 + ch * 8];

    float acc[8] = {0, 0, 0, 0, 0, 0, 0, 0};
    float cs = 0.0f;
    gatherC(&e2[(size_t)dst * BC], cntv, dst, hb, ch, acc, cs);

    float s = dd + cs;                         // normalized-adjacency rowsum
    u16x8 o;
#pragma unroll
    for (int j = 0; j < 8; j++) {
        float v = fmaf(dd, b2f(hs[j]), acc[j]);
        o[j] = f2b(fmaxf(fmaf(s, bmw1s[ch * 8 + j], v) + b1[ch * 8 + j], 0.0f));
    }
    ((u16x8*)aggb)[(size_t)dst * 8 + ch] = o;
}

// ---- D4 fused gather2 + final GEMM: out = (A_n*aggb)@W2 + b2, fp32 --------
__global__ __launch_bounds__(256) void g2gemm_k(const int2* __restrict__ e2,
                                                const int* __restrict__ count,
                                                const float* __restrict__ deg,
                                                const u16* __restrict__ aggb,
                                                const float* __restrict__ W2,
                                                const float* __restrict__ b2,
                                                float* __restrict__ out) {
    __shared__ u16 Wlds[4096];                  // 8 KB swizzled W2 frags
    __shared__ u16 Atile[32][72];               // 32x64 bf16, +8 pad
    int tid = threadIdx.x;
    for (int idx = tid; idx < 2 * 256; idx += 256) {
        int kt = idx >> 8, rem = idx & 255;
        int ct = rem >> 6, ln = rem & 63;
        int kb = kt * 32 + (ln >> 4) * 8;
        int col = ct * 16 + (ln & 15);
#pragma unroll
        for (int j = 0; j < 8; j++)
            Wlds[idx * 8 + j] = f2b(W2[(size_t)(kb + j) * 64 + col]);
    }

    int rt = tid >> 3, ch = tid & 7;
    int dst = blockIdx.x * 32 + rt;            // grid exact: 3125*32 == NN
    int cntv = min(count[dst], BC);
    float dd = 1.0f / (deg[dst] + 1.0f);
    u16x8 hs = *(const u16x8*)&aggb[(size_t)dst * 64 + ch * 8];

    float acc[8] = {0, 0, 0, 0, 0, 0, 0, 0};
    float cs = 0.0f;
    gatherC(&e2[(size_t)dst * BC], cntv, dst, aggb, ch, acc, cs);

    u16x8 o;
#pragma unroll
    for (int j = 0; j < 8; j++)
        o[j] = f2b(fmaf(dd, b2f(hs[j]), acc[j]));
    *(u16x8*)&Atile[rt][ch * 8] = o;
    __syncthreads();

    if (tid >= 128) return;                    // waves 0,1 compute the MFMA
    int wave = tid >> 6, lane = tid & 63;
    int m = lane & 15, quad = lane >> 4;
    int rowoff = wave * 16;
    f4 cacc[4];
#pragma unroll
    for (int ct = 0; ct < 4; ct++) cacc[ct] = 0.0f;
    const short8* Bfrag = (const short8*)Wlds;
#pragma unroll
    for (int kt = 0; kt < 2; kt++) {
        short8 af = *(const short8*)&Atile[rowoff + m][kt * 32 + quad * 8];
#pragma unroll
        for (int ct = 0; ct < 4; ct++)
            cacc[ct] = __builtin_amdgcn_mfma_f32_16x16x32_bf16(af, Bfrag[(kt * 4 + ct) * 64 + lane], cacc[ct], 0, 0, 0);
    }
    int rowbase = blockIdx.x * 32 + rowoff;
#pragma unroll
    for (int ct = 0; ct < 4; ct++) {
        int col = ct * 16 + m;
        float bc = b2[col];
#pragma unroll
        for (int rr = 0; rr < 4; rr++)
            out[(size_t)(rowbase + quad * 4 + rr) * 64 + col] = cacc[ct][rr] + bc;
    }
}

extern "C" void kernel_launch(void* const* d_in, const int* in_sizes, int n_in,
                              void* d_out, int out_size, void* d_ws, size_t ws_size,
                              hipStream_t stream) {
    const float* x  = (const float*)d_in[0];
    const int*   ei = (const int*)d_in[1];
    const float* ew = (const float*)d_in[2];
    const float* Wm = (const float*)d_in[3];
    const float* bm = (const float*)d_in[4];
    const float* W1 = (const float*)d_in[5];
    const float* b1 = (const float*)d_in[6];
    const float* W2 = (const float*)d_in[7];
    const float* b2 = (const float*)d_in[8];
    float* out = (float*)d_out;

    // ws layout (offsets in bytes)
    char*  w     = (char*)d_ws;
    float* deg   = (float*)(w);                 // NN f32 (400 KB)
    int*   count = (int*)(w + 400000);          // NN i32 (contiguous with deg)
    float* Wf    = (float*)(w + (1 << 20));     // 384*64 f32 (98 KB)
    int2*  e2    = (int2*)(w + (4 << 20));      // NN*BC int2 (25.6 MB)
    u16*   hb    = (u16*)(w + (64u << 20));     // NN*64 bf16 (12.8 MB)
    u16*   aggb  = (u16*)(w + (80u << 20));     // NN*64 bf16

    // D0: zero deg+count (800 KB contiguous)
    hipMemsetAsync(w, 0, 800000, stream);
    // D1: deg atomics || Wf = Wm@W1
    degwf_k<<<3131, 256, 0, stream>>>(ei, ew, deg, Wm, W1, Wf);
    // D2: hb = x@Wf (blocks 0..1562) || fill records (blocks 1563..4687)
    fillgemm_k<<<4688, 256, 0, stream>>>(ei, ew, deg, count, e2, x, Wf, hb);
    // D3: aggb = relu(A_n*hb + rowsum*(bm@W1) + b1)
    gather1_k<<<3125, 256, 0, stream>>>(e2, count, deg, hb, bm, W1, b1, aggb);
    // D4: out = (A_n*aggb)@W2 + b2
    g2gemm_k<<<3125, 256, 0, stream>>>(e2, count, deg, aggb, W2, b2, out);
}